// Round 6
// baseline (558.897 us; speedup 1.0000x reference)
//
#include <hip/hip_runtime.h>
#include <hip/hip_bf16.h>

// ============================================================
// 2-layer GCN. Per layer:
//   g = (X @ W) * dinv[row]   -- MFMA bf16 3-pass split-precision
//      (x=x_hi+x_lo, W=W_hi+W_lo; x_hi*W_hi + x_lo*W_hi + x_hi*W_lo,
//       fp32 accum; residual ~2^-17 => fp32-equivalent)
//   out_i = relu(dinv_i * (sum_{e:dst=i} g[src_e] + g_i) + b)
// g stored bf16; CSR gather aggregation; fp32 output.
// ============================================================

typedef __attribute__((ext_vector_type(8))) short bf16x8;
typedef __attribute__((ext_vector_type(4))) float f32x4;

__device__ inline unsigned short f2bf(float f) {        // RNE
    unsigned u = __float_as_uint(f);
    u = (u + 0x7fff + ((u >> 16) & 1)) >> 16;
    return (unsigned short)u;
}
__device__ inline float bf2f(unsigned short h) {
    return __uint_as_float(((unsigned)h) << 16);
}
__device__ inline float bflo(unsigned u) { return __uint_as_float(u << 16); }
__device__ inline float bfhi(unsigned u) { return __uint_as_float(u & 0xffff0000u); }

// ---------- degree histogram over dst ----------
__global__ void hist_kernel(const int* __restrict__ dst, int* __restrict__ deg, int E) {
    int stride = gridDim.x * blockDim.x;
    for (int i = blockIdx.x * blockDim.x + threadIdx.x; i < E; i += stride)
        atomicAdd(&deg[dst[i]], 1);
}

// ---------- scan pass 1: per-4096-block sums; also dinv = 1/sqrt(deg+1) ----------
__global__ __launch_bounds__(1024) void scan_partial_kernel(const int* __restrict__ deg,
        int* __restrict__ psum, float* __restrict__ dinv, int n) {
    __shared__ int wsum[16];
    int tid = threadIdx.x, wave = tid >> 6, lane = tid & 63;
    int i0 = blockIdx.x * 4096 + tid * 4;
    int v0 = 0, v1 = 0, v2 = 0, v3 = 0;
    if (i0 + 3 < n) {
        int4 v = *(const int4*)(deg + i0);
        v0 = v.x; v1 = v.y; v2 = v.z; v3 = v.w;
    } else {
        if (i0 + 0 < n) v0 = deg[i0 + 0];
        if (i0 + 1 < n) v1 = deg[i0 + 1];
        if (i0 + 2 < n) v2 = deg[i0 + 2];
        if (i0 + 3 < n) v3 = deg[i0 + 3];
    }
    if (i0 + 0 < n) dinv[i0 + 0] = 1.0f / sqrtf((float)v0 + 1.0f);
    if (i0 + 1 < n) dinv[i0 + 1] = 1.0f / sqrtf((float)v1 + 1.0f);
    if (i0 + 2 < n) dinv[i0 + 2] = 1.0f / sqrtf((float)v2 + 1.0f);
    if (i0 + 3 < n) dinv[i0 + 3] = 1.0f / sqrtf((float)v3 + 1.0f);
    int s = v0 + v1 + v2 + v3;
    #pragma unroll
    for (int off = 1; off < 64; off <<= 1) s += __shfl_xor(s, off, 64);
    if (lane == 0) wsum[wave] = s;
    __syncthreads();
    if (tid == 0) {
        int t = 0;
        #pragma unroll
        for (int w = 0; w < 16; ++w) t += wsum[w];
        psum[blockIdx.x] = t;
    }
}

// ---------- scan pass 2: exclusive scan of <=64 block sums; offs[n] = total ----------
__global__ void scan_base_kernel(int* __restrict__ psum, int* __restrict__ offs,
                                 int nb, int n) {
    int lane = threadIdx.x;
    int v = (lane < nb) ? psum[lane] : 0;
    int x = v;
    #pragma unroll
    for (int off = 1; off < 64; off <<= 1) {
        int y = __shfl_up(x, off, 64);
        if (lane >= off) x += y;
    }
    if (lane < nb) psum[lane] = x - v;   // exclusive base per block
    if (lane == 63) offs[n] = x;         // grand total
}

// ---------- scan pass 3: local scan + base -> offs ----------
__global__ __launch_bounds__(1024) void scan_local_kernel(const int* __restrict__ deg,
        const int* __restrict__ psum, int* __restrict__ offs, int n) {
    __shared__ int wsum[16];
    int tid = threadIdx.x, wave = tid >> 6, lane = tid & 63;
    int i0 = blockIdx.x * 4096 + tid * 4;
    int v0 = 0, v1 = 0, v2 = 0, v3 = 0;
    if (i0 + 3 < n) {
        int4 v = *(const int4*)(deg + i0);
        v0 = v.x; v1 = v.y; v2 = v.z; v3 = v.w;
    } else {
        if (i0 + 0 < n) v0 = deg[i0 + 0];
        if (i0 + 1 < n) v1 = deg[i0 + 1];
        if (i0 + 2 < n) v2 = deg[i0 + 2];
        if (i0 + 3 < n) v3 = deg[i0 + 3];
    }
    int s = v0 + v1 + v2 + v3;
    int x = s;
    #pragma unroll
    for (int off = 1; off < 64; off <<= 1) {
        int y = __shfl_up(x, off, 64);
        if (lane >= off) x += y;
    }
    if (lane == 63) wsum[wave] = x;
    __syncthreads();
    int wbase = 0;
    #pragma unroll
    for (int w = 0; w < 16; ++w)
        if (w < wave) wbase += wsum[w];
    int ex = psum[blockIdx.x] + wbase + (x - s);
    if (i0 + 0 < n) offs[i0 + 0] = ex;
    if (i0 + 1 < n) offs[i0 + 1] = ex + v0;
    if (i0 + 2 < n) offs[i0 + 2] = ex + v0 + v1;
    if (i0 + 3 < n) offs[i0 + 3] = ex + v0 + v1 + v2;
}

// ---------- CSR bucket fill ----------
__global__ void fill_kernel(const int* __restrict__ src, const int* __restrict__ dst,
        const int* __restrict__ offs, int* __restrict__ cursor,
        int* __restrict__ csr, int E) {
    int stride = gridDim.x * blockDim.x;
    for (int i = blockIdx.x * blockDim.x + threadIdx.x; i < E; i += stride) {
        int d = dst[i];
        int pos = offs[d] + atomicAdd(&cursor[d], 1);
        csr[pos] = src[i];
    }
}

// ---------- W split+transpose: W[K][N] fp32 -> Wt_hi/Wt_lo [N][K] bf16 ----------
__global__ void wsplit_kernel(const float* __restrict__ W,
        unsigned short* __restrict__ Wt_hi, unsigned short* __restrict__ Wt_lo,
        int K, int N) {
    int idx = blockIdx.x * 256 + threadIdx.x;
    if (idx >= K * N) return;
    int k = idx / N, n = idx - k * N;
    float v = W[idx];
    unsigned short h = f2bf(v);
    unsigned short l = f2bf(v - bf2f(h));
    Wt_hi[(size_t)n * K + k] = h;
    Wt_lo[(size_t)n * K + k] = l;
}

// ---------- MFMA GEMM: G[m][n] = bf16( dinv[m] * sum_k X[m][k] W[k][n] ) ----------
// 3-pass split precision; B-frags direct from global (Wt L1-resident);
// A staged fp32->hi/lo bf16 in LDS, padded rows (40 ushorts = 80B, 16B-aligned).
template <int K, int NT>   // NT = N/16
__global__ __launch_bounds__(256) void gemm_mfma_kernel(const float* __restrict__ X,
        const unsigned short* __restrict__ Wt_hi, const unsigned short* __restrict__ Wt_lo,
        const float* __restrict__ dinv, unsigned short* __restrict__ G, int M) {
    constexpr int N   = NT * 16;
    constexpr int BK  = 32;
    constexpr int LDA = BK + 8;                 // 40: bank-spread, keeps 16B align
    __shared__ unsigned short Ah[128 * LDA];
    __shared__ unsigned short Al[128 * LDA];

    const int tid  = threadIdx.x;
    const int wv   = tid >> 6, ln = tid & 63;
    const int l16  = ln & 15, kseg = ln >> 4;
    const int brow = blockIdx.x * 128;

    f32x4 acc[2][NT];
    #pragma unroll
    for (int a = 0; a < 2; ++a)
        #pragma unroll
        for (int b = 0; b < NT; ++b) acc[a][b] = 0;

    // staging geometry: thread -> (row, 16-wide k-chunk)
    const int srow = tid >> 1;
    const int scol = (tid & 1) * 16;
    int grow = brow + srow;
    if (grow >= M) grow = M - 1;                // clamp; stores guarded later
    const float* xrow = X + (size_t)grow * K + scol;
    unsigned int* ahw = (unsigned int*)&Ah[srow * LDA + scol];
    unsigned int* alw = (unsigned int*)&Al[srow * LDA + scol];

    const int arow = wv * 32;

    for (int k0 = 0; k0 < K; k0 += BK) {
        // ---- stage A tile: 16 fp32 per thread -> hi/lo bf16 pairs ----
        float4 q0 = *(const float4*)(xrow + k0 + 0);
        float4 q1 = *(const float4*)(xrow + k0 + 4);
        float4 q2 = *(const float4*)(xrow + k0 + 8);
        float4 q3 = *(const float4*)(xrow + k0 + 12);
        float v[16] = {q0.x,q0.y,q0.z,q0.w, q1.x,q1.y,q1.z,q1.w,
                       q2.x,q2.y,q2.z,q2.w, q3.x,q3.y,q3.z,q3.w};
        unsigned hw[8], lw[8];
        #pragma unroll
        for (int j = 0; j < 8; ++j) {
            unsigned short h0 = f2bf(v[2*j]),   h1 = f2bf(v[2*j+1]);
            unsigned short l0 = f2bf(v[2*j]   - bf2f(h0));
            unsigned short l1 = f2bf(v[2*j+1] - bf2f(h1));
            hw[j] = (unsigned)h0 | ((unsigned)h1 << 16);
            lw[j] = (unsigned)l0 | ((unsigned)l1 << 16);
        }
        *(uint4*)(ahw + 0) = make_uint4(hw[0], hw[1], hw[2], hw[3]);
        *(uint4*)(ahw + 4) = make_uint4(hw[4], hw[5], hw[6], hw[7]);
        *(uint4*)(alw + 0) = make_uint4(lw[0], lw[1], lw[2], lw[3]);
        *(uint4*)(alw + 4) = make_uint4(lw[4], lw[5], lw[6], lw[7]);
        __syncthreads();

        // ---- fragments ----
        bf16x8 a_h[2], a_l[2];
        #pragma unroll
        for (int tr = 0; tr < 2; ++tr) {
            a_h[tr] = *(const bf16x8*)&Ah[(arow + tr * 16 + l16) * LDA + kseg * 8];
            a_l[tr] = *(const bf16x8*)&Al[(arow + tr * 16 + l16) * LDA + kseg * 8];
        }
        #pragma unroll
        for (int tc = 0; tc < NT; ++tc) {
            size_t wo = (size_t)(tc * 16 + l16) * K + k0 + kseg * 8;
            bf16x8 b_h = *(const bf16x8*)(Wt_hi + wo);
            bf16x8 b_l = *(const bf16x8*)(Wt_lo + wo);
            #pragma unroll
            for (int tr = 0; tr < 2; ++tr) {
                acc[tr][tc] = __builtin_amdgcn_mfma_f32_16x16x32_bf16(a_h[tr], b_h, acc[tr][tc], 0, 0, 0);
                acc[tr][tc] = __builtin_amdgcn_mfma_f32_16x16x32_bf16(a_l[tr], b_h, acc[tr][tc], 0, 0, 0);
                acc[tr][tc] = __builtin_amdgcn_mfma_f32_16x16x32_bf16(a_h[tr], b_l, acc[tr][tc], 0, 0, 0);
            }
        }
        __syncthreads();
    }

    // ---- epilogue: scale by dinv, bf16 store (C/D: row=(ln>>4)*4+r, col=l16) ----
    #pragma unroll
    for (int tr = 0; tr < 2; ++tr) {
        int rbase = brow + arow + tr * 16 + (ln >> 4) * 4;
        #pragma unroll
        for (int r = 0; r < 4; ++r) {
            int row = rbase + r;
            if (row < M) {
                float dv = dinv[row];
                #pragma unroll
                for (int tc = 0; tc < NT; ++tc)
                    G[(size_t)row * N + tc * 16 + l16] = f2bf(acc[tr][tc][r] * dv);
            }
        }
    }
}

// ---------- aggregate, F=128 (bf16 rows as 64 uints), fp32 out ----------
__global__ __launch_bounds__(256) void aggregate128_kernel(const unsigned* __restrict__ G,
        const int* __restrict__ csr, const int* __restrict__ offs,
        const float* __restrict__ dinv, const float* __restrict__ bias,
        float* __restrict__ out, int n) {
    int wave = threadIdx.x >> 6, lane = threadIdx.x & 63;
    int node = blockIdx.x * 4 + wave;
    if (node >= n) return;
    int beg = offs[node], end = offs[node + 1];

    unsigned u = G[(size_t)node * 64 + lane];          // self loop
    float a0 = bflo(u), a1 = bfhi(u);
    int e = beg;
    for (; e + 4 <= end; e += 4) {                     // 4 rows in flight
        int s0 = csr[e], s1 = csr[e + 1], s2 = csr[e + 2], s3 = csr[e + 3];
        unsigned u0 = G[(size_t)s0 * 64 + lane];
        unsigned u1 = G[(size_t)s1 * 64 + lane];
        unsigned u2 = G[(size_t)s2 * 64 + lane];
        unsigned u3 = G[(size_t)s3 * 64 + lane];
        a0 += (bflo(u0) + bflo(u1)) + (bflo(u2) + bflo(u3));
        a1 += (bfhi(u0) + bfhi(u1)) + (bfhi(u2) + bfhi(u3));
    }
    for (; e < end; ++e) {
        unsigned u0 = G[(size_t)csr[e] * 64 + lane];
        a0 += bflo(u0);
        a1 += bfhi(u0);
    }
    float di = dinv[node];
    float2 r;
    r.x = fmaxf(fmaf(a0, di, bias[lane * 2 + 0]), 0.0f);
    r.y = fmaxf(fmaf(a1, di, bias[lane * 2 + 1]), 0.0f);
    ((float2*)(out + (size_t)node * 128))[lane] = r;
}

// ---------- aggregate, F=64 (bf16 rows as 32 uints), split-wave ----------
__global__ __launch_bounds__(256) void aggregate64_kernel(const unsigned* __restrict__ G,
        const int* __restrict__ csr, const int* __restrict__ offs,
        const float* __restrict__ dinv, const float* __restrict__ bias,
        float* __restrict__ out, int n) {
    int wave = threadIdx.x >> 6, lane = threadIdx.x & 63;
    int node = blockIdx.x * 4 + wave;
    if (node >= n) return;
    int beg = offs[node], end = offs[node + 1];
    int half = lane >> 5, col = lane & 31;

    float a0 = 0.0f, a1 = 0.0f;
    if (half == 0) {                                   // self loop on low half
        unsigned u = G[(size_t)node * 32 + col];
        a0 = bflo(u); a1 = bfhi(u);
    }
    int e = beg;
    for (; e + 4 <= end; e += 4) {                     // 4 edges/iter (2 per half)
        int sA = csr[e + half], sB = csr[e + 2 + half];
        unsigned uA = G[(size_t)sA * 32 + col];
        unsigned uB = G[(size_t)sB * 32 + col];
        a0 += bflo(uA) + bflo(uB);
        a1 += bfhi(uA) + bfhi(uB);
    }
    if (e + 2 <= end) {
        int sA = csr[e + half];
        unsigned uA = G[(size_t)sA * 32 + col];
        a0 += bflo(uA);
        a1 += bfhi(uA);
        e += 2;
    }
    if (e < end && half == 0) {                        // odd tail: low half only
        unsigned uA = G[(size_t)csr[e] * 32 + col];
        a0 += bflo(uA);
        a1 += bfhi(uA);
    }
    a0 += __shfl_down(a0, 32, 64);                     // fold high half into low
    a1 += __shfl_down(a1, 32, 64);
    if (half == 0) {
        float di = dinv[node];
        float2 r;
        r.x = fmaxf(fmaf(a0, di, bias[col * 2 + 0]), 0.0f);
        r.y = fmaxf(fmaf(a1, di, bias[col * 2 + 1]), 0.0f);
        ((float2*)(out + (size_t)node * 64))[col] = r;
    }
}

extern "C" void kernel_launch(void* const* d_in, const int* in_sizes, int n_in,
                              void* d_out, int out_size, void* d_ws, size_t ws_size,
                              hipStream_t stream) {
    const float* x  = (const float*)d_in[0];
    const float* W1 = (const float*)d_in[1];
    const float* b1 = (const float*)d_in[2];
    const float* W2 = (const float*)d_in[3];
    const float* b2 = (const float*)d_in[4];
    const int* edge = (const int*)d_in[5];

    const int IN = 256, H1 = 128, H2 = 64;
    const int E = in_sizes[5] / 2;
    const int N = in_sizes[0] / IN;
    const int* srcp = edge;
    const int* dstp = edge + E;

    char* ws = (char*)d_ws;
    auto alignup = [](size_t v) { return (v + 255) & ~(size_t)255; };
    size_t off = 0;
    size_t degSz = alignup((size_t)N * 4);
    int*            deg    = (int*)(ws + off);            off += degSz;
    int*            cursor = (int*)(ws + off);            off += degSz;
    int*            offs   = (int*)(ws + off);            off += alignup(((size_t)N + 1) * 4);
    float*          dinv   = (float*)(ws + off);          off += degSz;
    int*            psum   = (int*)(ws + off);            off += alignup(64 * 4);
    int*            csr    = (int*)(ws + off);            off += alignup((size_t)E * 4);
    unsigned short* wt1h   = (unsigned short*)(ws + off); off += alignup((size_t)IN * H1 * 2);
    unsigned short* wt1l   = (unsigned short*)(ws + off); off += alignup((size_t)IN * H1 * 2);
    unsigned short* wt2h   = (unsigned short*)(ws + off); off += alignup((size_t)H1 * H2 * 2);
    unsigned short* wt2l   = (unsigned short*)(ws + off); off += alignup((size_t)H1 * H2 * 2);
    unsigned short* g1     = (unsigned short*)(ws + off); off += alignup((size_t)N * H1 * 2);
    float*          h1     = (float*)(ws + off);          off += alignup((size_t)N * H1 * 4);
    unsigned short* g2     = g1;                          // g1 dead after aggregate1

    hipMemsetAsync(deg, 0, 2 * degSz, stream);   // deg + cursor contiguous

    int egrid = (E + 255) / 256;
    if (egrid > 2048) egrid = 2048;
    int sb = (N + 4095) / 4096;                  // 25 blocks (<=64 required)

    hist_kernel<<<egrid, 256, 0, stream>>>(dstp, deg, E);
    scan_partial_kernel<<<sb, 1024, 0, stream>>>(deg, psum, dinv, N);
    scan_base_kernel<<<1, 64, 0, stream>>>(psum, offs, sb, N);
    scan_local_kernel<<<sb, 1024, 0, stream>>>(deg, psum, offs, N);
    fill_kernel<<<egrid, 256, 0, stream>>>(srcp, dstp, offs, cursor, csr, E);
    wsplit_kernel<<<(IN * H1 + 255) / 256, 256, 0, stream>>>(W1, wt1h, wt1l, IN, H1);
    wsplit_kernel<<<(H1 * H2 + 255) / 256, 256, 0, stream>>>(W2, wt2h, wt2l, H1, H2);

    int mgrid = (N + 127) / 128;
    int agrid = (N + 3) / 4;

    // layer 1
    gemm_mfma_kernel<256, 8><<<mgrid, 256, 0, stream>>>(x, wt1h, wt1l, dinv, g1, N);
    aggregate128_kernel<<<agrid, 256, 0, stream>>>((const unsigned*)g1, csr, offs,
                                                   dinv, b1, h1, N);
    // layer 2
    gemm_mfma_kernel<128, 4><<<mgrid, 256, 0, stream>>>(h1, wt2h, wt2l, dinv, g2, N);
    aggregate64_kernel<<<agrid, 256, 0, stream>>>((const unsigned*)g2, csr, offs,
                                                  dinv, b2, (float*)d_out, N);
}

// Round 7
// 538.907 us; speedup vs baseline: 1.0371x; 1.0371x over previous
//
#include <hip/hip_runtime.h>
#include <hip/hip_bf16.h>

// ============================================================
// 2-layer GCN. Per layer:
//   g = (X @ W) * dinv[row]   -- MFMA bf16 3-pass split-precision
//      (x=x_hi+x_lo, W=W_hi+W_lo; fp32 accum; residual ~2^-17)
//   out_i = relu(dinv_i * (sum_{e:dst=i} g[src_e] + g_i) + b)
// g stored bf16; CSR gather aggregation; fp32 output.
// R7: BM=64 (6 blocks/CU), wave-quadrant split, X reg-prefetch.
// ============================================================

typedef __attribute__((ext_vector_type(8))) short bf16x8;
typedef __attribute__((ext_vector_type(4))) float f32x4;

__device__ inline unsigned short f2bf(float f) {        // RNE
    unsigned u = __float_as_uint(f);
    u = (u + 0x7fff + ((u >> 16) & 1)) >> 16;
    return (unsigned short)u;
}
__device__ inline float bf2f(unsigned short h) {
    return __uint_as_float(((unsigned)h) << 16);
}
__device__ inline float bflo(unsigned u) { return __uint_as_float(u << 16); }
__device__ inline float bfhi(unsigned u) { return __uint_as_float(u & 0xffff0000u); }

// ---------- degree histogram over dst ----------
__global__ void hist_kernel(const int* __restrict__ dst, int* __restrict__ deg, int E) {
    int stride = gridDim.x * blockDim.x;
    for (int i = blockIdx.x * blockDim.x + threadIdx.x; i < E; i += stride)
        atomicAdd(&deg[dst[i]], 1);
}

// ---------- scan pass 1: per-4096-block sums; also dinv = 1/sqrt(deg+1) ----------
__global__ __launch_bounds__(1024) void scan_partial_kernel(const int* __restrict__ deg,
        int* __restrict__ psum, float* __restrict__ dinv, int n) {
    __shared__ int wsum[16];
    int tid = threadIdx.x, wave = tid >> 6, lane = tid & 63;
    int i0 = blockIdx.x * 4096 + tid * 4;
    int v0 = 0, v1 = 0, v2 = 0, v3 = 0;
    if (i0 + 3 < n) {
        int4 v = *(const int4*)(deg + i0);
        v0 = v.x; v1 = v.y; v2 = v.z; v3 = v.w;
    } else {
        if (i0 + 0 < n) v0 = deg[i0 + 0];
        if (i0 + 1 < n) v1 = deg[i0 + 1];
        if (i0 + 2 < n) v2 = deg[i0 + 2];
        if (i0 + 3 < n) v3 = deg[i0 + 3];
    }
    if (i0 + 0 < n) dinv[i0 + 0] = 1.0f / sqrtf((float)v0 + 1.0f);
    if (i0 + 1 < n) dinv[i0 + 1] = 1.0f / sqrtf((float)v1 + 1.0f);
    if (i0 + 2 < n) dinv[i0 + 2] = 1.0f / sqrtf((float)v2 + 1.0f);
    if (i0 + 3 < n) dinv[i0 + 3] = 1.0f / sqrtf((float)v3 + 1.0f);
    int s = v0 + v1 + v2 + v3;
    #pragma unroll
    for (int off = 1; off < 64; off <<= 1) s += __shfl_xor(s, off, 64);
    if (lane == 0) wsum[wave] = s;
    __syncthreads();
    if (tid == 0) {
        int t = 0;
        #pragma unroll
        for (int w = 0; w < 16; ++w) t += wsum[w];
        psum[blockIdx.x] = t;
    }
}

// ---------- scan pass 2: exclusive scan of <=64 block sums; offs[n] = total ----------
__global__ void scan_base_kernel(int* __restrict__ psum, int* __restrict__ offs,
                                 int nb, int n) {
    int lane = threadIdx.x;
    int v = (lane < nb) ? psum[lane] : 0;
    int x = v;
    #pragma unroll
    for (int off = 1; off < 64; off <<= 1) {
        int y = __shfl_up(x, off, 64);
        if (lane >= off) x += y;
    }
    if (lane < nb) psum[lane] = x - v;   // exclusive base per block
    if (lane == 63) offs[n] = x;         // grand total
}

// ---------- scan pass 3: local scan + base -> offs ----------
__global__ __launch_bounds__(1024) void scan_local_kernel(const int* __restrict__ deg,
        const int* __restrict__ psum, int* __restrict__ offs, int n) {
    __shared__ int wsum[16];
    int tid = threadIdx.x, wave = tid >> 6, lane = tid & 63;
    int i0 = blockIdx.x * 4096 + tid * 4;
    int v0 = 0, v1 = 0, v2 = 0, v3 = 0;
    if (i0 + 3 < n) {
        int4 v = *(const int4*)(deg + i0);
        v0 = v.x; v1 = v.y; v2 = v.z; v3 = v.w;
    } else {
        if (i0 + 0 < n) v0 = deg[i0 + 0];
        if (i0 + 1 < n) v1 = deg[i0 + 1];
        if (i0 + 2 < n) v2 = deg[i0 + 2];
        if (i0 + 3 < n) v3 = deg[i0 + 3];
    }
    int s = v0 + v1 + v2 + v3;
    int x = s;
    #pragma unroll
    for (int off = 1; off < 64; off <<= 1) {
        int y = __shfl_up(x, off, 64);
        if (lane >= off) x += y;
    }
    if (lane == 63) wsum[wave] = x;
    __syncthreads();
    int wbase = 0;
    #pragma unroll
    for (int w = 0; w < 16; ++w)
        if (w < wave) wbase += wsum[w];
    int ex = psum[blockIdx.x] + wbase + (x - s);
    if (i0 + 0 < n) offs[i0 + 0] = ex;
    if (i0 + 1 < n) offs[i0 + 1] = ex + v0;
    if (i0 + 2 < n) offs[i0 + 2] = ex + v0 + v1;
    if (i0 + 3 < n) offs[i0 + 3] = ex + v0 + v1 + v2;
}

// ---------- CSR bucket fill ----------
__global__ void fill_kernel(const int* __restrict__ src, const int* __restrict__ dst,
        const int* __restrict__ offs, int* __restrict__ cursor,
        int* __restrict__ csr, int E) {
    int stride = gridDim.x * blockDim.x;
    for (int i = blockIdx.x * blockDim.x + threadIdx.x; i < E; i += stride) {
        int d = dst[i];
        int pos = offs[d] + atomicAdd(&cursor[d], 1);
        csr[pos] = src[i];
    }
}

// ---------- W split+transpose: W[K][N] fp32 -> Wt_hi/Wt_lo [N][K] bf16 ----------
__global__ void wsplit_kernel(const float* __restrict__ W,
        unsigned short* __restrict__ Wt_hi, unsigned short* __restrict__ Wt_lo,
        int K, int N) {
    int idx = blockIdx.x * 256 + threadIdx.x;
    if (idx >= K * N) return;
    int k = idx / N, n = idx - k * N;
    float v = W[idx];
    unsigned short h = f2bf(v);
    unsigned short l = f2bf(v - bf2f(h));
    Wt_hi[(size_t)n * K + k] = h;
    Wt_lo[(size_t)n * K + k] = l;
}

// ---------- MFMA GEMM: G[m][n] = bf16( dinv[m] * sum_k X[m][k] W[k][n] ) ----------
// BM=64 rows/block, 4 waves as NWR x NWC grid of quadrants (RW=NWC row-tiles,
// CW=N/16/NWC col-tiles per wave). 3-pass split precision. X reg-prefetch.
template <int K, int N, int NWC>
__global__ __launch_bounds__(256) void gemm_mfma_kernel(const float* __restrict__ X,
        const unsigned short* __restrict__ Wt_hi, const unsigned short* __restrict__ Wt_lo,
        const float* __restrict__ dinv, unsigned short* __restrict__ G, int M) {
    constexpr int BK  = 32;
    constexpr int BM  = 64;
    constexpr int LDA = BK + 8;                // 40 ushorts = 80B rows (16B-aligned)
    constexpr int RW  = NWC;                   // row-tiles per wave
    constexpr int CW  = N / 16 / NWC;          // col-tiles per wave
    __shared__ unsigned short Ah[BM * LDA];
    __shared__ unsigned short Al[BM * LDA];

    const int tid  = threadIdx.x;
    const int wv   = tid >> 6, ln = tid & 63;
    const int l16  = ln & 15, kseg = ln >> 4;
    const int wc   = wv % NWC, wr = wv / NWC;
    const int brow = blockIdx.x * BM;

    f32x4 acc[RW][CW];
    #pragma unroll
    for (int a = 0; a < RW; ++a)
        #pragma unroll
        for (int b = 0; b < CW; ++b) acc[a][b] = 0;

    // staging: 256 threads cover 64 rows x 32 k; 8 fp32 per thread
    const int srow = tid >> 2;
    const int scol = (tid & 3) * 8;
    int grow = brow + srow;
    if (grow >= M) grow = M - 1;               // clamp; stores guarded later
    const float* xp = X + (size_t)grow * K + scol;
    unsigned int* ahw = (unsigned int*)&Ah[srow * LDA + scol];
    unsigned int* alw = (unsigned int*)&Al[srow * LDA + scol];

    float4 qa = *(const float4*)(xp);          // prologue load, tile 0
    float4 qb = *(const float4*)(xp + 4);

    for (int k0 = 0; k0 < K; k0 += BK) {
        // ---- convert staged regs -> hi/lo bf16, write LDS ----
        float v[8] = {qa.x, qa.y, qa.z, qa.w, qb.x, qb.y, qb.z, qb.w};
        unsigned hw[4], lw[4];
        #pragma unroll
        for (int j = 0; j < 4; ++j) {
            unsigned short h0 = f2bf(v[2*j]),   h1 = f2bf(v[2*j+1]);
            unsigned short l0 = f2bf(v[2*j]   - bf2f(h0));
            unsigned short l1 = f2bf(v[2*j+1] - bf2f(h1));
            hw[j] = (unsigned)h0 | ((unsigned)h1 << 16);
            lw[j] = (unsigned)l0 | ((unsigned)l1 << 16);
        }
        *(uint4*)ahw = make_uint4(hw[0], hw[1], hw[2], hw[3]);
        *(uint4*)alw = make_uint4(lw[0], lw[1], lw[2], lw[3]);
        __syncthreads();

        // ---- issue next X tile early (consumed next iteration) ----
        if (k0 + BK < K) {
            qa = *(const float4*)(xp + k0 + BK);
            qb = *(const float4*)(xp + k0 + BK + 4);
        }

        // ---- fragments + MFMA ----
        bf16x8 a_h[RW], a_l[RW];
        #pragma unroll
        for (int tr = 0; tr < RW; ++tr) {
            int ar = wr * (RW * 16) + tr * 16 + l16;
            a_h[tr] = *(const bf16x8*)&Ah[ar * LDA + kseg * 8];
            a_l[tr] = *(const bf16x8*)&Al[ar * LDA + kseg * 8];
        }
        #pragma unroll
        for (int tc = 0; tc < CW; ++tc) {
            size_t wo = (size_t)(wc * (CW * 16) + tc * 16 + l16) * K + k0 + kseg * 8;
            bf16x8 b_h = *(const bf16x8*)(Wt_hi + wo);
            bf16x8 b_l = *(const bf16x8*)(Wt_lo + wo);
            #pragma unroll
            for (int tr = 0; tr < RW; ++tr) {
                acc[tr][tc] = __builtin_amdgcn_mfma_f32_16x16x32_bf16(a_h[tr], b_h, acc[tr][tc], 0, 0, 0);
                acc[tr][tc] = __builtin_amdgcn_mfma_f32_16x16x32_bf16(a_l[tr], b_h, acc[tr][tc], 0, 0, 0);
                acc[tr][tc] = __builtin_amdgcn_mfma_f32_16x16x32_bf16(a_h[tr], b_l, acc[tr][tc], 0, 0, 0);
            }
        }
        __syncthreads();                       // protect LDS before next write
    }

    // ---- epilogue: scale by dinv, bf16 store (C/D: row=(ln>>4)*4+r, col=l16) ----
    #pragma unroll
    for (int tr = 0; tr < RW; ++tr) {
        int rbase = brow + wr * (RW * 16) + tr * 16 + (ln >> 4) * 4;
        #pragma unroll
        for (int r = 0; r < 4; ++r) {
            int row = rbase + r;
            if (row < M) {
                float dv = dinv[row];
                #pragma unroll
                for (int tc = 0; tc < CW; ++tc)
                    G[(size_t)row * N + wc * (CW * 16) + tc * 16 + l16] =
                        f2bf(acc[tr][tc][r] * dv);
            }
        }
    }
}

// ---------- aggregate, F=128 (bf16 rows as 64 uints), fp32 out ----------
__global__ __launch_bounds__(256) void aggregate128_kernel(const unsigned* __restrict__ G,
        const int* __restrict__ csr, const int* __restrict__ offs,
        const float* __restrict__ dinv, const float* __restrict__ bias,
        float* __restrict__ out, int n) {
    int wave = threadIdx.x >> 6, lane = threadIdx.x & 63;
    int node = blockIdx.x * 4 + wave;
    if (node >= n) return;
    int beg = offs[node], end = offs[node + 1];

    unsigned u = G[(size_t)node * 64 + lane];          // self loop
    float a0 = bflo(u), a1 = bfhi(u);
    int e = beg;
    for (; e + 4 <= end; e += 4) {                     // 4 rows in flight
        int s0 = csr[e], s1 = csr[e + 1], s2 = csr[e + 2], s3 = csr[e + 3];
        unsigned u0 = G[(size_t)s0 * 64 + lane];
        unsigned u1 = G[(size_t)s1 * 64 + lane];
        unsigned u2 = G[(size_t)s2 * 64 + lane];
        unsigned u3 = G[(size_t)s3 * 64 + lane];
        a0 += (bflo(u0) + bflo(u1)) + (bflo(u2) + bflo(u3));
        a1 += (bfhi(u0) + bfhi(u1)) + (bfhi(u2) + bfhi(u3));
    }
    for (; e < end; ++e) {
        unsigned u0 = G[(size_t)csr[e] * 64 + lane];
        a0 += bflo(u0);
        a1 += bfhi(u0);
    }
    float di = dinv[node];
    float2 r;
    r.x = fmaxf(fmaf(a0, di, bias[lane * 2 + 0]), 0.0f);
    r.y = fmaxf(fmaf(a1, di, bias[lane * 2 + 1]), 0.0f);
    ((float2*)(out + (size_t)node * 128))[lane] = r;
}

// ---------- aggregate, F=64 (bf16 rows as 32 uints), split-wave ----------
__global__ __launch_bounds__(256) void aggregate64_kernel(const unsigned* __restrict__ G,
        const int* __restrict__ csr, const int* __restrict__ offs,
        const float* __restrict__ dinv, const float* __restrict__ bias,
        float* __restrict__ out, int n) {
    int wave = threadIdx.x >> 6, lane = threadIdx.x & 63;
    int node = blockIdx.x * 4 + wave;
    if (node >= n) return;
    int beg = offs[node], end = offs[node + 1];
    int half = lane >> 5, col = lane & 31;

    float a0 = 0.0f, a1 = 0.0f;
    if (half == 0) {                                   // self loop on low half
        unsigned u = G[(size_t)node * 32 + col];
        a0 = bflo(u); a1 = bfhi(u);
    }
    int e = beg;
    for (; e + 4 <= end; e += 4) {                     // 4 edges/iter (2 per half)
        int sA = csr[e + half], sB = csr[e + 2 + half];
        unsigned uA = G[(size_t)sA * 32 + col];
        unsigned uB = G[(size_t)sB * 32 + col];
        a0 += bflo(uA) + bflo(uB);
        a1 += bfhi(uA) + bfhi(uB);
    }
    if (e + 2 <= end) {
        int sA = csr[e + half];
        unsigned uA = G[(size_t)sA * 32 + col];
        a0 += bflo(uA);
        a1 += bfhi(uA);
        e += 2;
    }
    if (e < end && half == 0) {                        // odd tail: low half only
        unsigned uA = G[(size_t)csr[e] * 32 + col];
        a0 += bflo(uA);
        a1 += bfhi(uA);
    }
    a0 += __shfl_down(a0, 32, 64);                     // fold high half into low
    a1 += __shfl_down(a1, 32, 64);
    if (half == 0) {
        float di = dinv[node];
        float2 r;
        r.x = fmaxf(fmaf(a0, di, bias[col * 2 + 0]), 0.0f);
        r.y = fmaxf(fmaf(a1, di, bias[col * 2 + 1]), 0.0f);
        ((float2*)(out + (size_t)node * 64))[col] = r;
    }
}

extern "C" void kernel_launch(void* const* d_in, const int* in_sizes, int n_in,
                              void* d_out, int out_size, void* d_ws, size_t ws_size,
                              hipStream_t stream) {
    const float* x  = (const float*)d_in[0];
    const float* W1 = (const float*)d_in[1];
    const float* b1 = (const float*)d_in[2];
    const float* W2 = (const float*)d_in[3];
    const float* b2 = (const float*)d_in[4];
    const int* edge = (const int*)d_in[5];

    const int IN = 256, H1 = 128, H2 = 64;
    const int E = in_sizes[5] / 2;
    const int N = in_sizes[0] / IN;
    const int* srcp = edge;
    const int* dstp = edge + E;

    char* ws = (char*)d_ws;
    auto alignup = [](size_t v) { return (v + 255) & ~(size_t)255; };
    size_t off = 0;
    size_t degSz = alignup((size_t)N * 4);
    int*            deg    = (int*)(ws + off);            off += degSz;
    int*            cursor = (int*)(ws + off);            off += degSz;
    int*            offs   = (int*)(ws + off);            off += alignup(((size_t)N + 1) * 4);
    float*          dinv   = (float*)(ws + off);          off += degSz;
    int*            psum   = (int*)(ws + off);            off += alignup(64 * 4);
    int*            csr    = (int*)(ws + off);            off += alignup((size_t)E * 4);
    unsigned short* wt1h   = (unsigned short*)(ws + off); off += alignup((size_t)IN * H1 * 2);
    unsigned short* wt1l   = (unsigned short*)(ws + off); off += alignup((size_t)IN * H1 * 2);
    unsigned short* wt2h   = (unsigned short*)(ws + off); off += alignup((size_t)H1 * H2 * 2);
    unsigned short* wt2l   = (unsigned short*)(ws + off); off += alignup((size_t)H1 * H2 * 2);
    unsigned short* g1     = (unsigned short*)(ws + off); off += alignup((size_t)N * H1 * 2);
    float*          h1     = (float*)(ws + off);          off += alignup((size_t)N * H1 * 4);
    unsigned short* g2     = g1;                          // g1 dead after aggregate1

    hipMemsetAsync(deg, 0, 2 * degSz, stream);   // deg + cursor contiguous

    int egrid = (E + 255) / 256;
    if (egrid > 2048) egrid = 2048;
    int sb = (N + 4095) / 4096;                  // 25 blocks (<=64 required)

    hist_kernel<<<egrid, 256, 0, stream>>>(dstp, deg, E);
    scan_partial_kernel<<<sb, 1024, 0, stream>>>(deg, psum, dinv, N);
    scan_base_kernel<<<1, 64, 0, stream>>>(psum, offs, sb, N);
    scan_local_kernel<<<sb, 1024, 0, stream>>>(deg, psum, offs, N);
    fill_kernel<<<egrid, 256, 0, stream>>>(srcp, dstp, offs, cursor, csr, E);
    wsplit_kernel<<<(IN * H1 + 255) / 256, 256, 0, stream>>>(W1, wt1h, wt1l, IN, H1);
    wsplit_kernel<<<(H1 * H2 + 255) / 256, 256, 0, stream>>>(W2, wt2h, wt2l, H1, H2);

    int mgrid = (N + 63) / 64;                   // BM=64 -> 1563 blocks
    int agrid = (N + 3) / 4;

    // layer 1
    gemm_mfma_kernel<256, 128, 2><<<mgrid, 256, 0, stream>>>(x, wt1h, wt1l, dinv, g1, N);
    aggregate128_kernel<<<agrid, 256, 0, stream>>>((const unsigned*)g1, csr, offs,
                                                   dinv, b1, h1, N);
    // layer 2
    gemm_mfma_kernel<128, 64, 1><<<mgrid, 256, 0, stream>>>(h1, wt2h, wt2l, dinv, g2, N);
    aggregate64_kernel<<<agrid, 256, 0, stream>>>((const unsigned*)g2, csr, offs,
                                                  dinv, b2, (float*)d_out, N);
}

// Round 8
// 526.132 us; speedup vs baseline: 1.0623x; 1.0243x over previous
//
#include <hip/hip_runtime.h>
#include <hip/hip_bf16.h>

// ============================================================
// 2-layer GCN. Per layer:
//   g = (X @ W) * dinv[row]   -- MFMA bf16 split-precision
//   out_i = relu(dinv_i * (sum_{e:dst=i} g[src_e] + g_i) + b)
// R8: barrier-free reg-direct MFMA GEMMs; fill fused into gemm1
// launch; h1 stored bf16; wsplit fused into hist launch.
// ============================================================

typedef __attribute__((ext_vector_type(8))) short bf16x8;
typedef __attribute__((ext_vector_type(4))) float f32x4;

__device__ inline unsigned short f2bf(float f) {        // RNE
    unsigned u = __float_as_uint(f);
    u = (u + 0x7fff + ((u >> 16) & 1)) >> 16;
    return (unsigned short)u;
}
__device__ inline float bf2f(unsigned short h) {
    return __uint_as_float(((unsigned)h) << 16);
}
__device__ inline float bflo(unsigned u) { return __uint_as_float(u << 16); }
__device__ inline float bfhi(unsigned u) { return __uint_as_float(u & 0xffff0000u); }
__device__ inline unsigned pack_bf16_2(float lo, float hi) {
    return (unsigned)f2bf(lo) | ((unsigned)f2bf(hi) << 16);
}
__device__ inline void cvt8(const float* v, bf16x8& h8, bf16x8& l8) {
    #pragma unroll
    for (int j = 0; j < 8; ++j) {
        unsigned short h = f2bf(v[j]);
        h8[j] = (short)h;
        l8[j] = (short)f2bf(v[j] - bf2f(h));
    }
}

// ---------- prep: wsplit(W1) + wsplit(W2) + degree histogram ----------
__global__ void prep_kernel(const int* __restrict__ dst, int* __restrict__ deg, int E,
        const float* __restrict__ W1, unsigned short* __restrict__ w1h,
        unsigned short* __restrict__ w1l,
        const float* __restrict__ W2, unsigned short* __restrict__ w2h,
        unsigned short* __restrict__ w2l) {
    const int W1B = (256 * 128) / 256;   // 128 blocks
    const int W2B = (128 * 64) / 256;    // 32 blocks
    int b = blockIdx.x;
    if (b < W1B) {                        // W1 split+transpose [K=256][N=128]
        int idx = b * 256 + threadIdx.x;
        int k = idx >> 7, n = idx & 127;
        float v = W1[idx];
        unsigned short h = f2bf(v);
        w1h[(size_t)n * 256 + k] = h;
        w1l[(size_t)n * 256 + k] = f2bf(v - bf2f(h));
    } else if (b < W1B + W2B) {           // W2 split+transpose [K=128][N=64]
        int idx = (b - W1B) * 256 + threadIdx.x;
        int k = idx >> 6, n = idx & 63;
        float v = W2[idx];
        unsigned short h = f2bf(v);
        w2h[(size_t)n * 128 + k] = h;
        w2l[(size_t)n * 128 + k] = f2bf(v - bf2f(h));
    } else {                              // histogram
        int nb = gridDim.x - (W1B + W2B);
        int stride = nb * 256;
        for (int i = (b - W1B - W2B) * 256 + threadIdx.x; i < E; i += stride)
            atomicAdd(&deg[dst[i]], 1);
    }
}

// ---------- scan pass 1: per-4096-block sums; also dinv = 1/sqrt(deg+1) ----------
__global__ __launch_bounds__(1024) void scan_partial_kernel(const int* __restrict__ deg,
        int* __restrict__ psum, float* __restrict__ dinv, int n) {
    __shared__ int wsum[16];
    int tid = threadIdx.x, wave = tid >> 6, lane = tid & 63;
    int i0 = blockIdx.x * 4096 + tid * 4;
    int v0 = 0, v1 = 0, v2 = 0, v3 = 0;
    if (i0 + 3 < n) {
        int4 v = *(const int4*)(deg + i0);
        v0 = v.x; v1 = v.y; v2 = v.z; v3 = v.w;
    } else {
        if (i0 + 0 < n) v0 = deg[i0 + 0];
        if (i0 + 1 < n) v1 = deg[i0 + 1];
        if (i0 + 2 < n) v2 = deg[i0 + 2];
        if (i0 + 3 < n) v3 = deg[i0 + 3];
    }
    if (i0 + 0 < n) dinv[i0 + 0] = 1.0f / sqrtf((float)v0 + 1.0f);
    if (i0 + 1 < n) dinv[i0 + 1] = 1.0f / sqrtf((float)v1 + 1.0f);
    if (i0 + 2 < n) dinv[i0 + 2] = 1.0f / sqrtf((float)v2 + 1.0f);
    if (i0 + 3 < n) dinv[i0 + 3] = 1.0f / sqrtf((float)v3 + 1.0f);
    int s = v0 + v1 + v2 + v3;
    #pragma unroll
    for (int off = 1; off < 64; off <<= 1) s += __shfl_xor(s, off, 64);
    if (lane == 0) wsum[wave] = s;
    __syncthreads();
    if (tid == 0) {
        int t = 0;
        #pragma unroll
        for (int w = 0; w < 16; ++w) t += wsum[w];
        psum[blockIdx.x] = t;
    }
}

// ---------- scan pass 2: exclusive scan of <=64 block sums ----------
__global__ void scan_base_kernel(int* __restrict__ psum, int* __restrict__ offs,
                                 int nb, int n) {
    int lane = threadIdx.x;
    int v = (lane < nb) ? psum[lane] : 0;
    int x = v;
    #pragma unroll
    for (int off = 1; off < 64; off <<= 1) {
        int y = __shfl_up(x, off, 64);
        if (lane >= off) x += y;
    }
    if (lane < nb) psum[lane] = x - v;
    if (lane == 63) offs[n] = x;
}

// ---------- scan pass 3: local scan + base -> offs ----------
__global__ __launch_bounds__(1024) void scan_local_kernel(const int* __restrict__ deg,
        const int* __restrict__ psum, int* __restrict__ offs, int n) {
    __shared__ int wsum[16];
    int tid = threadIdx.x, wave = tid >> 6, lane = tid & 63;
    int i0 = blockIdx.x * 4096 + tid * 4;
    int v0 = 0, v1 = 0, v2 = 0, v3 = 0;
    if (i0 + 3 < n) {
        int4 v = *(const int4*)(deg + i0);
        v0 = v.x; v1 = v.y; v2 = v.z; v3 = v.w;
    } else {
        if (i0 + 0 < n) v0 = deg[i0 + 0];
        if (i0 + 1 < n) v1 = deg[i0 + 1];
        if (i0 + 2 < n) v2 = deg[i0 + 2];
        if (i0 + 3 < n) v3 = deg[i0 + 3];
    }
    int s = v0 + v1 + v2 + v3;
    int x = s;
    #pragma unroll
    for (int off = 1; off < 64; off <<= 1) {
        int y = __shfl_up(x, off, 64);
        if (lane >= off) x += y;
    }
    if (lane == 63) wsum[wave] = x;
    __syncthreads();
    int wbase = 0;
    #pragma unroll
    for (int w = 0; w < 16; ++w)
        if (w < wave) wbase += wsum[w];
    int ex = psum[blockIdx.x] + wbase + (x - s);
    if (i0 + 0 < n) offs[i0 + 0] = ex;
    if (i0 + 1 < n) offs[i0 + 1] = ex + v0;
    if (i0 + 2 < n) offs[i0 + 2] = ex + v0 + v1;
    if (i0 + 3 < n) offs[i0 + 3] = ex + v0 + v1 + v2;
}

// ---------- fused: CSR fill + layer-1 GEMM (barrier-free, reg-direct) ----------
// blocks [0, NF): fill. blocks [NF, NF+NG): gemm1 (BM=128, 4 waves x 32 rows,
// CW=8 col-tiles, K=256, 3-pass split precision, no LDS, no barriers).
__global__ __launch_bounds__(256) void fused_fill_gemm1(
        const int* __restrict__ src, const int* __restrict__ dst,
        const int* __restrict__ offs, int* __restrict__ cursor,
        int* __restrict__ csr, int E, int NF,
        const float* __restrict__ X,
        const unsigned short* __restrict__ Wh, const unsigned short* __restrict__ Wl,
        const float* __restrict__ dinv, unsigned short* __restrict__ G, int M) {
    if ((int)blockIdx.x < NF) {                       // ---- fill role ----
        int stride = NF * 256;
        for (int i = blockIdx.x * 256 + threadIdx.x; i < E; i += stride) {
            int d = dst[i];
            int pos = offs[d] + atomicAdd(&cursor[d], 1);
            csr[pos] = src[i];
        }
        return;
    }
    // ---- gemm1 role ----
    constexpr int K = 256;
    const int bid = blockIdx.x - NF;
    const int tid = threadIdx.x;
    const int wv = tid >> 6, ln = tid & 63;
    const int l16 = ln & 15, kseg = ln >> 4;
    const int r0 = bid * 128 + wv * 32;

    int rA0 = r0 + l16;       if (rA0 >= M) rA0 = M - 1;
    int rA1 = r0 + 16 + l16;  if (rA1 >= M) rA1 = M - 1;
    const float* pA0 = X + (size_t)rA0 * K + kseg * 8;
    const float* pA1 = X + (size_t)rA1 * K + kseg * 8;

    f32x4 acc[2][8];
    #pragma unroll
    for (int a = 0; a < 2; ++a)
        #pragma unroll
        for (int b = 0; b < 8; ++b) acc[a][b] = 0;

    #pragma unroll 2
    for (int k0 = 0; k0 < K; k0 += 32) {
        bf16x8 ah[2], al[2];
        {
            float4 qa = *(const float4*)(pA0 + k0);
            float4 qb = *(const float4*)(pA0 + k0 + 4);
            float v[8] = {qa.x, qa.y, qa.z, qa.w, qb.x, qb.y, qb.z, qb.w};
            cvt8(v, ah[0], al[0]);
        }
        {
            float4 qa = *(const float4*)(pA1 + k0);
            float4 qb = *(const float4*)(pA1 + k0 + 4);
            float v[8] = {qa.x, qa.y, qa.z, qa.w, qb.x, qb.y, qb.z, qb.w};
            cvt8(v, ah[1], al[1]);
        }
        #pragma unroll
        for (int tc = 0; tc < 8; ++tc) {
            size_t wo = (size_t)(tc * 16 + l16) * K + k0 + kseg * 8;
            bf16x8 bh = *(const bf16x8*)(Wh + wo);
            bf16x8 bl = *(const bf16x8*)(Wl + wo);
            #pragma unroll
            for (int tr = 0; tr < 2; ++tr) {
                acc[tr][tc] = __builtin_amdgcn_mfma_f32_16x16x32_bf16(ah[tr], bh, acc[tr][tc], 0, 0, 0);
                acc[tr][tc] = __builtin_amdgcn_mfma_f32_16x16x32_bf16(al[tr], bh, acc[tr][tc], 0, 0, 0);
                acc[tr][tc] = __builtin_amdgcn_mfma_f32_16x16x32_bf16(ah[tr], bl, acc[tr][tc], 0, 0, 0);
            }
        }
    }

    #pragma unroll
    for (int tr = 0; tr < 2; ++tr) {
        int rbase = r0 + tr * 16 + (ln >> 4) * 4;
        #pragma unroll
        for (int r = 0; r < 4; ++r) {
            int row = rbase + r;
            if (row < M) {
                float dv = dinv[row];
                #pragma unroll
                for (int tc = 0; tc < 8; ++tc)
                    G[(size_t)row * 128 + tc * 16 + l16] = f2bf(acc[tr][tc][r] * dv);
            }
        }
    }
}

// ---------- layer-2 GEMM: A = bf16 h1 direct, W2 split hi/lo (2 MFMA/tile) ----------
__global__ __launch_bounds__(256) void gemm2_kernel(const unsigned short* __restrict__ H,
        const unsigned short* __restrict__ Wh, const unsigned short* __restrict__ Wl,
        const float* __restrict__ dinv, unsigned short* __restrict__ G, int M) {
    constexpr int K = 128;
    const int tid = threadIdx.x;
    const int wv = tid >> 6, ln = tid & 63;
    const int l16 = ln & 15, kseg = ln >> 4;
    const int r0 = blockIdx.x * 128 + wv * 32;

    int rA0 = r0 + l16;       if (rA0 >= M) rA0 = M - 1;
    int rA1 = r0 + 16 + l16;  if (rA1 >= M) rA1 = M - 1;
    const unsigned short* pA0 = H + (size_t)rA0 * K + kseg * 8;
    const unsigned short* pA1 = H + (size_t)rA1 * K + kseg * 8;

    f32x4 acc[2][4];
    #pragma unroll
    for (int a = 0; a < 2; ++a)
        #pragma unroll
        for (int b = 0; b < 4; ++b) acc[a][b] = 0;

    #pragma unroll
    for (int k0 = 0; k0 < K; k0 += 32) {
        bf16x8 a0 = *(const bf16x8*)(pA0 + k0);
        bf16x8 a1 = *(const bf16x8*)(pA1 + k0);
        #pragma unroll
        for (int tc = 0; tc < 4; ++tc) {
            size_t wo = (size_t)(tc * 16 + l16) * K + k0 + kseg * 8;
            bf16x8 bh = *(const bf16x8*)(Wh + wo);
            bf16x8 bl = *(const bf16x8*)(Wl + wo);
            acc[0][tc] = __builtin_amdgcn_mfma_f32_16x16x32_bf16(a0, bh, acc[0][tc], 0, 0, 0);
            acc[0][tc] = __builtin_amdgcn_mfma_f32_16x16x32_bf16(a0, bl, acc[0][tc], 0, 0, 0);
            acc[1][tc] = __builtin_amdgcn_mfma_f32_16x16x32_bf16(a1, bh, acc[1][tc], 0, 0, 0);
            acc[1][tc] = __builtin_amdgcn_mfma_f32_16x16x32_bf16(a1, bl, acc[1][tc], 0, 0, 0);
        }
    }

    #pragma unroll
    for (int tr = 0; tr < 2; ++tr) {
        int rbase = r0 + tr * 16 + (ln >> 4) * 4;
        #pragma unroll
        for (int r = 0; r < 4; ++r) {
            int row = rbase + r;
            if (row < M) {
                float dv = dinv[row];
                #pragma unroll
                for (int tc = 0; tc < 4; ++tc)
                    G[(size_t)row * 64 + tc * 16 + l16] = f2bf(acc[tr][tc][r] * dv);
            }
        }
    }
}

// ---------- aggregate, F=128, bf16 in / bf16 packed out (h1) ----------
__global__ __launch_bounds__(256) void aggregate128_kernel(const unsigned* __restrict__ G,
        const int* __restrict__ csr, const int* __restrict__ offs,
        const float* __restrict__ dinv, const float* __restrict__ bias,
        unsigned* __restrict__ out, int n) {
    int wave = threadIdx.x >> 6, lane = threadIdx.x & 63;
    int node = blockIdx.x * 4 + wave;
    if (node >= n) return;
    int beg = offs[node], end = offs[node + 1];

    unsigned u = G[(size_t)node * 64 + lane];          // self loop
    float a0 = bflo(u), a1 = bfhi(u);
    int e = beg;
    for (; e + 4 <= end; e += 4) {                     // 4 rows in flight
        int s0 = csr[e], s1 = csr[e + 1], s2 = csr[e + 2], s3 = csr[e + 3];
        unsigned u0 = G[(size_t)s0 * 64 + lane];
        unsigned u1 = G[(size_t)s1 * 64 + lane];
        unsigned u2 = G[(size_t)s2 * 64 + lane];
        unsigned u3 = G[(size_t)s3 * 64 + lane];
        a0 += (bflo(u0) + bflo(u1)) + (bflo(u2) + bflo(u3));
        a1 += (bfhi(u0) + bfhi(u1)) + (bfhi(u2) + bfhi(u3));
    }
    for (; e < end; ++e) {
        unsigned u0 = G[(size_t)csr[e] * 64 + lane];
        a0 += bflo(u0);
        a1 += bfhi(u0);
    }
    float di = dinv[node];
    float rx = fmaxf(fmaf(a0, di, bias[lane * 2 + 0]), 0.0f);
    float ry = fmaxf(fmaf(a1, di, bias[lane * 2 + 1]), 0.0f);
    out[(size_t)node * 64 + lane] = pack_bf16_2(rx, ry);
}

// ---------- aggregate, F=64, bf16 in / fp32 out, split-wave ----------
__global__ __launch_bounds__(256) void aggregate64_kernel(const unsigned* __restrict__ G,
        const int* __restrict__ csr, const int* __restrict__ offs,
        const float* __restrict__ dinv, const float* __restrict__ bias,
        float* __restrict__ out, int n) {
    int wave = threadIdx.x >> 6, lane = threadIdx.x & 63;
    int node = blockIdx.x * 4 + wave;
    if (node >= n) return;
    int beg = offs[node], end = offs[node + 1];
    int half = lane >> 5, col = lane & 31;

    float a0 = 0.0f, a1 = 0.0f;
    if (half == 0) {                                   // self loop on low half
        unsigned u = G[(size_t)node * 32 + col];
        a0 = bflo(u); a1 = bfhi(u);
    }
    int e = beg;
    for (; e + 4 <= end; e += 4) {                     // 4 edges/iter (2 per half)
        int sA = csr[e + half], sB = csr[e + 2 + half];
        unsigned uA = G[(size_t)sA * 32 + col];
        unsigned uB = G[(size_t)sB * 32 + col];
        a0 += bflo(uA) + bflo(uB);
        a1 += bfhi(uA) + bfhi(uB);
    }
    if (e + 2 <= end) {
        int sA = csr[e + half];
        unsigned uA = G[(size_t)sA * 32 + col];
        a0 += bflo(uA);
        a1 += bfhi(uA);
        e += 2;
    }
    if (e < end && half == 0) {
        unsigned uA = G[(size_t)csr[e] * 32 + col];
        a0 += bflo(uA);
        a1 += bfhi(uA);
    }
    a0 += __shfl_down(a0, 32, 64);
    a1 += __shfl_down(a1, 32, 64);
    if (half == 0) {
        float di = dinv[node];
        float2 r;
        r.x = fmaxf(fmaf(a0, di, bias[col * 2 + 0]), 0.0f);
        r.y = fmaxf(fmaf(a1, di, bias[col * 2 + 1]), 0.0f);
        ((float2*)(out + (size_t)node * 64))[col] = r;
    }
}

extern "C" void kernel_launch(void* const* d_in, const int* in_sizes, int n_in,
                              void* d_out, int out_size, void* d_ws, size_t ws_size,
                              hipStream_t stream) {
    const float* x  = (const float*)d_in[0];
    const float* W1 = (const float*)d_in[1];
    const float* b1 = (const float*)d_in[2];
    const float* W2 = (const float*)d_in[3];
    const float* b2 = (const float*)d_in[4];
    const int* edge = (const int*)d_in[5];

    const int IN = 256, H1 = 128, H2 = 64;
    const int E = in_sizes[5] / 2;
    const int N = in_sizes[0] / IN;
    const int* srcp = edge;
    const int* dstp = edge + E;

    char* ws = (char*)d_ws;
    auto alignup = [](size_t v) { return (v + 255) & ~(size_t)255; };
    size_t off = 0;
    size_t degSz = alignup((size_t)N * 4);
    int*            deg    = (int*)(ws + off);            off += degSz;
    int*            cursor = (int*)(ws + off);            off += degSz;
    int*            offs   = (int*)(ws + off);            off += alignup(((size_t)N + 1) * 4);
    float*          dinv   = (float*)(ws + off);          off += degSz;
    int*            psum   = (int*)(ws + off);            off += alignup(64 * 4);
    int*            csr    = (int*)(ws + off);            off += alignup((size_t)E * 4);
    unsigned short* wt1h   = (unsigned short*)(ws + off); off += alignup((size_t)IN * H1 * 2);
    unsigned short* wt1l   = (unsigned short*)(ws + off); off += alignup((size_t)IN * H1 * 2);
    unsigned short* wt2h   = (unsigned short*)(ws + off); off += alignup((size_t)H1 * H2 * 2);
    unsigned short* wt2l   = (unsigned short*)(ws + off); off += alignup((size_t)H1 * H2 * 2);
    unsigned short* g1     = (unsigned short*)(ws + off); off += alignup((size_t)N * H1 * 2);
    unsigned*       h1b    = (unsigned*)(ws + off);       off += alignup((size_t)N * (H1 / 2) * 4);
    unsigned short* g2     = g1;                          // g1 dead after aggregate1

    hipMemsetAsync(deg, 0, 2 * degSz, stream);   // deg + cursor contiguous

    int hgrid = 2048;
    int sb = (N + 4095) / 4096;                  // 25 blocks (<=64 required)

    prep_kernel<<<160 + hgrid, 256, 0, stream>>>(dstp, deg, E, W1, wt1h, wt1l,
                                                 W2, wt2h, wt2l);
    scan_partial_kernel<<<sb, 1024, 0, stream>>>(deg, psum, dinv, N);
    scan_base_kernel<<<1, 64, 0, stream>>>(psum, offs, sb, N);
    scan_local_kernel<<<sb, 1024, 0, stream>>>(deg, psum, offs, N);

    const int NF = 1024;                         // fill blocks
    const int NG = (N + 127) / 128;              // gemm1 blocks (782)
    fused_fill_gemm1<<<NF + NG, 256, 0, stream>>>(srcp, dstp, offs, cursor, csr, E,
                                                  NF, x, wt1h, wt1l, dinv, g1, N);

    int agrid = (N + 3) / 4;
    aggregate128_kernel<<<agrid, 256, 0, stream>>>((const unsigned*)g1, csr, offs,
                                                   dinv, b1, h1b, N);
    gemm2_kernel<<<NG, 256, 0, stream>>>((const unsigned short*)h1b, wt2h, wt2l,
                                         dinv, g2, N);
    aggregate64_kernel<<<agrid, 256, 0, stream>>>((const unsigned*)g2, csr, offs,
                                                  dinv, b2, (float*)d_out, N);
}